// Round 1
// baseline (263.488 us; speedup 1.0000x reference)
//
#include <hip/hip_runtime.h>

typedef unsigned short u16;
typedef unsigned int u32;

typedef __attribute__((ext_vector_type(8))) short bfrag;   // 8 bf16 lanes for MFMA A/B
typedef __attribute__((ext_vector_type(4))) float f32x4;
typedef __attribute__((ext_vector_type(8))) u16 u16x8;

constexpr int S = 2048;
constexpr int HN = 16;

__device__ __forceinline__ u16 f2b(float f) {
  u32 u = __builtin_bit_cast(u32, f);
  return (u16)((u + 0x7FFFu + ((u >> 16) & 1u)) >> 16);  // RNE f32->bf16
}

__device__ __forceinline__ f32x4 mfma16(bfrag a, bfrag b, f32x4 c) {
  return __builtin_amdgcn_mfma_f32_16x16x32_bf16(a, b, c, 0, 0, 0);
}

__device__ __forceinline__ void gload_lds16(const void* g, void* l) {
  __builtin_amdgcn_global_load_lds(
      (const __attribute__((address_space(1))) u32*)g,
      (__attribute__((address_space(3))) u32*)l, 16, 0, 0);
}

// ---------------- W transpose + f32->bf16:  WT[n][k] = (bf16) W[k][n] ----------------
__global__ __launch_bounds__(256) void wtrans_kernel(
    const float* __restrict__ W0, const float* __restrict__ W1,
    const float* __restrict__ W2, const float* __restrict__ W3,
    u16* __restrict__ ws)
{
  const float* W = blockIdx.z == 0 ? W0 : blockIdx.z == 1 ? W1 : blockIdx.z == 2 ? W2 : W3;
  u16* WT = ws + (size_t)blockIdx.z * (1u << 20);
  __shared__ u16 tile[64 * 65];
  const int t = threadIdx.x;
  const int k0 = blockIdx.y * 64, n0 = blockIdx.x * 64;
#pragma unroll
  for (int i = 0; i < 4; ++i) {
    int idx = i * 256 + t;
    int r = idx >> 4, c4 = (idx & 15) * 4;
    float4 v = *(const float4*)&W[(size_t)(k0 + r) * 1024 + n0 + c4];
    tile[r * 65 + c4 + 0] = f2b(v.x);
    tile[r * 65 + c4 + 1] = f2b(v.y);
    tile[r * 65 + c4 + 2] = f2b(v.z);
    tile[r * 65 + c4 + 3] = f2b(v.w);
  }
  __syncthreads();
#pragma unroll
  for (int i = 0; i < 2; ++i) {
    int idx = i * 256 + t;
    int n = idx >> 3, k8 = (idx & 7) * 8;
    u16x8 o;
#pragma unroll
    for (int j = 0; j < 8; ++j) o[j] = tile[(k8 + j) * 65 + n];
    *(u16x8*)&WT[(size_t)(n0 + n) * 1024 + k0 + k8] = o;
  }
}

// ---------------- v [B,H,S,64] -> vT [B,H,64,S] (bf16) ----------------
__global__ __launch_bounds__(256) void vtrans_kernel(
    const u16* __restrict__ v, u16* __restrict__ vT)
{
  __shared__ u16 tile[64 * 65];
  const int t = threadIdx.x;
  const int s0 = blockIdx.x * 64;
  const int bh = blockIdx.y;
#pragma unroll
  for (int i = 0; i < 2; ++i) {
    int idx = i * 256 + t;
    int r = idx >> 3, c8 = (idx & 7) * 8;
    u16x8 in = *(const u16x8*)&v[((size_t)bh * S + s0 + r) * 64 + c8];
#pragma unroll
    for (int j = 0; j < 8; ++j) tile[r * 65 + c8 + j] = in[j];
  }
  __syncthreads();
#pragma unroll
  for (int i = 0; i < 2; ++i) {
    int idx = i * 256 + t;
    int d = idx >> 3, s8 = (idx & 7) * 8;
    u16x8 o;
#pragma unroll
    for (int j = 0; j < 8; ++j) o[j] = tile[(s8 + j) * 65 + d];
    *(u16x8*)&vT[((size_t)bh * 64 + d) * S + s0 + s8] = o;
  }
}

// ---------------- GEMM: C[M,N] = A[M,K] * Bt[N,K]^T + bias ----------------
// AMODE 0: A is f32 (converted to bf16 while staging); 1: A is bf16.
// CMODE 0: scatter-store bf16 to [B,H,S,64]; 1: f32 linear [M,N].
template <int AMODE, int CMODE>
__global__ __launch_bounds__(256) void gemm_bt(
    const void* __restrict__ Av, const u16* __restrict__ Bt,
    const float* __restrict__ bias, void* __restrict__ Cout,
    int M, int N, int K)
{
  __shared__ __align__(16) u16 As[128 * 64];
  __shared__ __align__(16) u16 Bs[128 * 64];
  const int tid = threadIdx.x;
  const int wid = tid >> 6, lane = tid & 63;
  const int g = lane >> 4, c = lane & 15;
  const int bn = blockIdx.x, bm = blockIdx.y;
  const int wr = wid >> 1, wc = wid & 1;

  f32x4 acc[4][4] = {};

  const int nkt = K >> 6;
  for (int kt = 0; kt < nkt; ++kt) {
    if (AMODE == 0) {
      const float* A = (const float*)Av;
#pragma unroll
      for (int p = 0; p < 4; ++p) {
        int e = (p * 256 + tid) * 8;
        int row = e >> 6, col = e & 63;
        const float* src = &A[(size_t)(bm * 128 + row) * K + kt * 64 + col];
        float4 v0 = *(const float4*)src;
        float4 v1 = *(const float4*)(src + 4);
        u16x8 w;
        w[0] = f2b(v0.x); w[1] = f2b(v0.y); w[2] = f2b(v0.z); w[3] = f2b(v0.w);
        w[4] = f2b(v1.x); w[5] = f2b(v1.y); w[6] = f2b(v1.z); w[7] = f2b(v1.w);
        *(u16x8*)&As[row * 64 + (col ^ ((row & 7) << 3))] = w;
      }
    } else {
      const u16* A = (const u16*)Av;
#pragma unroll
      for (int p = 0; p < 4; ++p) {
        int e = (p * 256 + tid) * 8;
        int row = e >> 6, col = e & 63;
        u16x8 w = *(const u16x8*)&A[(size_t)(bm * 128 + row) * K + kt * 64 + col];
        *(u16x8*)&As[row * 64 + (col ^ ((row & 7) << 3))] = w;
      }
    }
    // B tile via global_load_lds, source pre-swizzled so reads can XOR-deswizzle
#pragma unroll
    for (int p = 0; p < 4; ++p) {
      int off = (p * 4 + wid) * 1024 + (lane << 4);
      int row = off >> 7, colb = off & 127;
      const u16* src = &Bt[(size_t)(bn * 128 + row) * K + kt * 64 +
                           ((colb ^ ((row & 7) << 4)) >> 1)];
      gload_lds16(src, (char*)Bs + (p * 4 + wid) * 1024);
    }
    __syncthreads();

#pragma unroll
    for (int ks = 0; ks < 2; ++ks) {
      bfrag af[4], bf[4];
#pragma unroll
      for (int mi = 0; mi < 4; ++mi) {
        int row = wr * 64 + mi * 16 + c;
        af[mi] = *(const bfrag*)&As[row * 64 + ((ks * 32 + g * 8) ^ ((row & 7) << 3))];
      }
#pragma unroll
      for (int ni = 0; ni < 4; ++ni) {
        int row = wc * 64 + ni * 16 + c;
        bf[ni] = *(const bfrag*)&Bs[row * 64 + ((ks * 32 + g * 8) ^ ((row & 7) << 3))];
      }
#pragma unroll
      for (int mi = 0; mi < 4; ++mi)
#pragma unroll
        for (int ni = 0; ni < 4; ++ni)
          acc[mi][ni] = mfma16(af[mi], bf[ni], acc[mi][ni]);
    }
    __syncthreads();
  }

#pragma unroll
  for (int mi = 0; mi < 4; ++mi) {
#pragma unroll
    for (int ni = 0; ni < 4; ++ni) {
#pragma unroll
      for (int j = 0; j < 4; ++j) {
        int rowg = bm * 128 + wr * 64 + mi * 16 + g * 4 + j;
        int colg = bn * 128 + wc * 64 + ni * 16 + c;
        float val = acc[mi][ni][j] + bias[colg];
        if (CMODE == 0) {
          int b = rowg >> 11, s = rowg & (S - 1);
          int h = colg >> 6, d = colg & 63;
          ((u16*)Cout)[((size_t)((b * HN + h) * S + s)) * 64 + d] = f2b(val);
        } else {
          ((float*)Cout)[(size_t)rowg * N + colg] = val;
        }
      }
    }
  }
}

// ---------------- flash attention over ALL key tiles (pad + causal via -1e9) ----------------
__global__ __launch_bounds__(256) void attn_kernel(
    const u16* __restrict__ q, const u16* __restrict__ k,
    const u16* __restrict__ vT, const int* __restrict__ pad,
    u16* __restrict__ ao)
{
  __shared__ __align__(16) u16 Ks[64 * 64];
  __shared__ __align__(16) u16 Vs[64 * 64];
  __shared__ __align__(16) int pads[2048];
  __shared__ __align__(16) u16 Ps[4][16 * 72];

  const int tid = threadIdx.x;
  const int wid = tid >> 6, lane = tid & 63;
  const int g = lane >> 4, c = lane & 15;
  const int qt = blockIdx.x, bh = blockIdx.y;
  const int b = bh >> 4;

#pragma unroll
  for (int i = 0; i < 2; ++i) {
    int idx = (i * 256 + tid) * 4;
    *(int4*)&pads[idx] = *(const int4*)&pad[b * S + idx];
  }

  const int qrow_frag = qt * 64 + wid * 16 + c;
  bfrag qf[2];
#pragma unroll
  for (int ks = 0; ks < 2; ++ks)
    qf[ks] = *(const bfrag*)&q[((size_t)bh * S + qrow_frag) * 64 + ks * 32 + g * 8];

  float m[4], lsum[4];
  f32x4 acc[4];
#pragma unroll
  for (int j = 0; j < 4; ++j) { m[j] = -3.0e38f; lsum[j] = 0.f; }
#pragma unroll
  for (int nf = 0; nf < 4; ++nf) acc[nf] = f32x4{0.f, 0.f, 0.f, 0.f};

  __syncthreads();

  for (int kt = 0; kt < 32; ++kt) {
    // stage K tile [64 keys][64 d] and V^T tile [64 dv][64 keys], XOR-swizzled
#pragma unroll
    for (int p = 0; p < 2; ++p) {
      int off = (wid * 2 + p) * 1024 + (lane << 4);
      int row = off >> 7, colb = off & 127;
      gload_lds16(&k[((size_t)bh * S + kt * 64 + row) * 64 + ((colb ^ ((row & 7) << 4)) >> 1)],
                  (char*)Ks + (wid * 2 + p) * 1024);
    }
#pragma unroll
    for (int p = 0; p < 2; ++p) {
      int off = (wid * 2 + p) * 1024 + (lane << 4);
      int row = off >> 7, colb = off & 127;
      gload_lds16(&vT[((size_t)bh * 64 + row) * S + kt * 64 + ((colb ^ ((row & 7) << 4)) >> 1)],
                  (char*)Vs + (wid * 2 + p) * 1024);
    }
    __syncthreads();

    // QK^T: D[qlocal 16][key 64]
    f32x4 sc[4];
#pragma unroll
    for (int nf = 0; nf < 4; ++nf) sc[nf] = f32x4{0.f, 0.f, 0.f, 0.f};
#pragma unroll
    for (int ks = 0; ks < 2; ++ks) {
#pragma unroll
      for (int nf = 0; nf < 4; ++nf) {
        int row = nf * 16 + c;
        bfrag kf = *(const bfrag*)&Ks[row * 64 + ((ks * 32 + g * 8) ^ ((row & 7) << 3))];
        sc[nf] = mfma16(qf[ks], kf, sc[nf]);
      }
    }

    // mask exactly like reference: masked score := -1e9 (exact in f32)
    float sval[4][4];
#pragma unroll
    for (int nf = 0; nf < 4; ++nf) {
      int key = kt * 64 + nf * 16 + c;
      bool padm = pads[key] != 0;
#pragma unroll
      for (int j = 0; j < 4; ++j) {
        int qrow = qt * 64 + wid * 16 + g * 4 + j;
        sval[nf][j] = (padm || key > qrow) ? -1e9f : sc[nf][j] * 0.125f;
      }
    }

    // online softmax per q row (row = lanes sharing g, replicated across 16 lanes)
#pragma unroll
    for (int j = 0; j < 4; ++j) {
      float pm = fmaxf(fmaxf(sval[0][j], sval[1][j]), fmaxf(sval[2][j], sval[3][j]));
#pragma unroll
      for (int o = 1; o < 16; o <<= 1) pm = fmaxf(pm, __shfl_xor(pm, o));
      float mn = fmaxf(m[j], pm);
      float fac = __expf(m[j] - mn);
      float rs = 0.f;
#pragma unroll
      for (int nf = 0; nf < 4; ++nf) {
        float pv = __expf(sval[nf][j] - mn);
        Ps[wid][(g * 4 + j) * 72 + nf * 16 + c] = f2b(pv);
        rs += pv;
      }
#pragma unroll
      for (int o = 1; o < 16; o <<= 1) rs += __shfl_xor(rs, o);
      lsum[j] = lsum[j] * fac + rs;
      m[j] = mn;
#pragma unroll
      for (int nf = 0; nf < 4; ++nf) acc[nf][j] *= fac;
    }

    // PV: A = P (via wave-private LDS relayout), B = V^T tile
#pragma unroll
    for (int ks = 0; ks < 2; ++ks) {
      bfrag pa = *(const bfrag*)&Ps[wid][c * 72 + ks * 32 + g * 8];
#pragma unroll
      for (int nf = 0; nf < 4; ++nf) {
        int row = nf * 16 + c;
        bfrag vb = *(const bfrag*)&Vs[row * 64 + ((ks * 32 + g * 8) ^ ((row & 7) << 3))];
        acc[nf] = mfma16(pa, vb, acc[nf]);
      }
    }
    __syncthreads();
  }

  const int h = bh & 15;
#pragma unroll
  for (int nf = 0; nf < 4; ++nf) {
#pragma unroll
    for (int j = 0; j < 4; ++j) {
      int qrow = qt * 64 + wid * 16 + g * 4 + j;
      int col = h * 64 + nf * 16 + c;
      ao[((size_t)b * S + qrow) * 1024 + col] = f2b(acc[nf][j] / lsum[j]);
    }
  }
}

// ---------------- launch ----------------
extern "C" void kernel_launch(void* const* d_in, const int* in_sizes, int n_in,
                              void* d_out, int out_size, void* d_ws, size_t ws_size,
                              hipStream_t stream)
{
  const float* Q  = (const float*)d_in[0];
  const float* Kk = (const float*)d_in[1];
  const float* V  = (const float*)d_in[2];
  const int* pad  = (const int*)d_in[3];
  const float* Wq = (const float*)d_in[4];
  const float* bq = (const float*)d_in[5];
  const float* Wk = (const float*)d_in[6];
  const float* bk = (const float*)d_in[7];
  const float* Wv = (const float*)d_in[8];
  const float* bv = (const float*)d_in[9];
  const float* Wo = (const float*)d_in[10];
  const float* bo = (const float*)d_in[11];

  // ws layout (u16 elems): 4 x WT (1M each) | q (4M) | k (4M) | v/ao (4M) | vT (4M) = 40 MiB
  u16* ws  = (u16*)d_ws;
  u16* WqT = ws + 0 * (size_t)(1u << 20);
  u16* WkT = ws + 1 * (size_t)(1u << 20);
  u16* WvT = ws + 2 * (size_t)(1u << 20);
  u16* WoT = ws + 3 * (size_t)(1u << 20);
  u16* qb  = ws + 4 * (size_t)(1u << 20);
  u16* kb  = ws + 8 * (size_t)(1u << 20);
  u16* vb  = ws + 12 * (size_t)(1u << 20);
  u16* vTb = ws + 16 * (size_t)(1u << 20);
  u16* ao  = vb;  // v is dead after vtrans; reuse for attention output

  wtrans_kernel<<<dim3(16, 16, 4), 256, 0, stream>>>(Wq, Wk, Wv, Wo, ws);
  gemm_bt<0, 0><<<dim3(8, 32), 256, 0, stream>>>(Q,  WqT, bq, qb, 4096, 1024, 1024);
  gemm_bt<0, 0><<<dim3(8, 32), 256, 0, stream>>>(Kk, WkT, bk, kb, 4096, 1024, 1024);
  gemm_bt<0, 0><<<dim3(8, 32), 256, 0, stream>>>(V,  WvT, bv, vb, 4096, 1024, 1024);
  vtrans_kernel<<<dim3(32, 32), 256, 0, stream>>>(vb, vTb);
  attn_kernel<<<dim3(32, 32), 256, 0, stream>>>(qb, kb, vTb, pad, ao);
  gemm_bt<1, 1><<<dim3(8, 32), 256, 0, stream>>>(ao, WoT, bo, d_out, 4096, 1024, 1024);
}